// Round 3
// 562.826 us; speedup vs baseline: 1.0006x; 1.0006x over previous
//
#include <hip/hip_runtime.h>
#include <hip/hip_bf16.h>

typedef __attribute__((ext_vector_type(4))) float floatx4;
typedef __attribute__((ext_vector_type(8))) __bf16 bf16x8;
typedef unsigned short ushort_t;

#define NENT  700
#define EMB   256
#define KDIM  1024
#define NDIM  512
#define HROWS 720   // 45*16: every row written by hab_kernel; reads stay <= 709
#define NPAIR 340000

// ws byte offsets — total ~7.4 MB
#define WS_HA   0
#define WS_HB   (WS_HA + HROWS*KDIM*2)
#define WS_W2H  (WS_HB + HROWS*KDIM*2)
#define WS_ENT  (WS_W2H + NDIM*KDIM*2)
#define WS_LG   (WS_ENT + NENT*EMB*4)

__device__ __forceinline__ float ldin(const void* p, int i, int isbf) {
    return isbf ? __bfloat162float(((const __hip_bfloat16*)p)[i])
                : ((const float*)p)[i];
}

// per-wave dtype sniff of entity_embedding; deterministic, no cross-kernel dep
__device__ __forceinline__ int detect_bf16(const ushort_t* __restrict__ w) {
    int t = threadIdx.x & 63;
    int e = (w[2*t] >> 7) & 0xFF;
    unsigned long long m = __ballot(e >= 100 && e <= 126);
    return (__popcll(m) >= 48) ? 1 : 0;   // bf16 ~64 hits, f32 ~7
}

// lgkmcnt(0) only; vmcnt untouched -> global prefetches survive the barrier
#define LDS_BARRIER() do { __builtin_amdgcn_s_waitcnt(0xC07F); __builtin_amdgcn_s_barrier(); } while (0)

// ---------------- stage 1: ent (88 blocks) + W2 repack (256 blocks), one launch ----------------
__global__ void entprep_kernel(const void* __restrict__ E, const void* __restrict__ Went,
                               const void* __restrict__ W2,
                               float* __restrict__ ent, __hip_bfloat16* __restrict__ W2H,
                               void* __restrict__ out) {
    int isbf = detect_bf16((const ushort_t*)E);
    if (blockIdx.x < 88) {
        int ib = blockIdx.x * 8, t = threadIdx.x;
        __shared__ float rows[8][EMB];
#pragma unroll
        for (int r = 0; r < 8; ++r) {
            int i = ib + r;
            rows[r][t] = (i < NENT) ? ldin(E, i*EMB + t, isbf) : 0.f;
        }
        __syncthreads();
        float acc[8] = {0.f,0.f,0.f,0.f,0.f,0.f,0.f,0.f};
        if (isbf) {
            const __hip_bfloat16* W = (const __hip_bfloat16*)Went;
            for (int k = 0; k < EMB; ++k) {
                float w = __bfloat162float(W[k*EMB + t]);
#pragma unroll
                for (int r = 0; r < 8; ++r) acc[r] += rows[r][k] * w;
            }
        } else {
            const float* W = (const float*)Went;
            for (int k = 0; k < EMB; ++k) {
                float w = W[k*EMB + t];
#pragma unroll
                for (int r = 0; r < 8; ++r) acc[r] += rows[r][k] * w;
            }
        }
#pragma unroll
        for (int r = 0; r < 8; ++r) {
            int i = ib + r;
            if (i < NENT) {
                ent[i*EMB + t] = acc[r];
                if (i < 200) {
                    if (isbf) ((__hip_bfloat16*)out)[680000 + i*EMB + t] = __float2bfloat16(acc[r]);
                    else      ((float*)out)[680000 + i*EMB + t] = acc[r];
                }
            }
        }
    } else {
        // W2H: elem ((half*32+kc)*16 + f)*512 + lane*8 + j
        //   = bf16(W2[(kc*32 + (lane>>4)*8 + j)*512 + half*256 + f*16 + (lane&15)])
        int g = (blockIdx.x - 88)*256 + threadIdx.x;     // 65536
        int lane = g & 63, f = (g >> 6) & 15, kc = (g >> 10) & 31, half = g >> 15;
        int l15 = lane & 15, quad = lane >> 4;
        int n = half*256 + f*16 + l15;
        bf16x8 v;
#pragma unroll
        for (int j = 0; j < 8; ++j) {
            int k = kc*32 + quad*8 + j;
            v[j] = (__bf16)ldin(W2, k*NDIM + n, isbf);
        }
        *(bf16x8*)(W2H + (size_t)g*8) = v;
    }
}

// ---------------- stage 2: HA/HB, 16 rows/block ----------------
__global__ void hab_kernel(const float* __restrict__ ent, const void* __restrict__ E,
                           const void* __restrict__ W1, const void* __restrict__ b1,
                           __hip_bfloat16* __restrict__ HA, __hip_bfloat16* __restrict__ HB) {
    int isbf = detect_bf16((const ushort_t*)E);
    int part = blockIdx.y;
    int ib = blockIdx.x * 16;
    int t = threadIdx.x;
    __shared__ float rows[16][EMB];
#pragma unroll
    for (int r = 0; r < 16; ++r) {
        int i = ib + r;
        rows[r][t] = (i < NENT) ? ent[i*EMB + t] : 0.f;
    }
    __syncthreads();
    float acc[16][4];
#pragma unroll
    for (int r = 0; r < 16; ++r)
#pragma unroll
        for (int p = 0; p < 4; ++p) acc[r][p] = 0.f;

    int wbase = part*EMB*KDIM;
    if (isbf) {
        const __hip_bfloat16* W = (const __hip_bfloat16*)W1;
        for (int k = 0; k < EMB; ++k) {
            float w[4];
#pragma unroll
            for (int p = 0; p < 4; ++p) w[p] = __bfloat162float(W[wbase + k*KDIM + t + p*256]);
#pragma unroll
            for (int r = 0; r < 16; ++r) {
                float e = rows[r][k];
#pragma unroll
                for (int p = 0; p < 4; ++p) acc[r][p] += e * w[p];
            }
        }
    } else {
        const float* W = (const float*)W1;
        for (int k = 0; k < EMB; ++k) {
            float w[4];
#pragma unroll
            for (int p = 0; p < 4; ++p) w[p] = W[wbase + k*KDIM + t + p*256];
#pragma unroll
            for (int r = 0; r < 16; ++r) {
                float e = rows[r][k];
#pragma unroll
                for (int p = 0; p < 4; ++p) acc[r][p] += e * w[p];
            }
        }
    }
    __hip_bfloat16* HX = part ? HB : HA;
#pragma unroll
    for (int r = 0; r < 16; ++r) {
#pragma unroll
        for (int p = 0; p < 4; ++p) {
            int n = t + p*256;
            float v = acc[r][p];
            if (!part) v += ldin(b1, n, isbf);
            HX[(ib + r)*KDIM + n] = __float2bfloat16(v);
        }
    }
}

union U8 { bf16x8 v; unsigned u[4]; };

// relu(ha + hb) -> bf16 round-half-up, pair-packed via v_perm
__device__ __forceinline__ bf16x8 mk_af3(bf16x8 ha, bf16x8 hb) {
    U8 r;
#pragma unroll
    for (int j = 0; j < 4; ++j) {
        float x0 = fmaxf((float)ha[2*j]   + (float)hb[2*j],   0.f);
        float x1 = fmaxf((float)ha[2*j+1] + (float)hb[2*j+1], 0.f);
        unsigned u0 = __float_as_uint(x0) + 0x8000u;
        unsigned u1 = __float_as_uint(x1) + 0x8000u;
#if defined(__has_builtin) && __has_builtin(__builtin_amdgcn_perm)
        r.u[j] = __builtin_amdgcn_perm(u1, u0, 0x07060302u);  // {u1.hi16, u0.hi16}
#else
        r.u[j] = (u0 >> 16) | (u1 & 0xFFFF0000u);
#endif
    }
    return r.v;
}

#define MFMA(a, b, c) __builtin_amdgcn_mfma_f32_16x16x32_bf16((a), (b), (c), 0, 0, 0)

// ---------------- main: fused pair MLP ----------------
// R15 == R13 with the R14 transcription bug fixed (sub-1 acc[2][3] line had
// wrong operands -> absmax 2.1e-2). One 8-wave block owns M=64 x N=512 x
// K=1024. Wave w = (half = w>>2, n64-slice = w&3). Per phase the 8 A-frags
// (4 m-frags x 2 kc) map 1:1 onto the 8 waves -> A-gen VALU + HA/HB loads +
// LDS writes HALVED per MFMA vs the (5582,2) grid. Block produces final
// logits: b3 + softmax fused, final_kernel gone.
__global__ __launch_bounds__(512, 2) void pair_kernel(
        const ushort_t* __restrict__ HA, const ushort_t* __restrict__ HB,
        const ushort_t* __restrict__ W2H, const void* __restrict__ E,
        const void* __restrict__ b2, const void* __restrict__ W3,
        const void* __restrict__ b3, void* __restrict__ out) {

    const int blkEnd[10] = {650,1300,1800,2300,2800,3450,4100,4594,5088,5582};
    const int aB[10]  = {0,0,0,0,200,200,200,550,400,400};
    const int bB[10]  = {200,0,400,550,400,200,0,0,200,0};
    const int NaT[10] = {200,200,200,200,200,200,200,150,150,150};
    const int NbT[10] = {200,200,150,150,150,200,200,200,200,200};
    const int jTl[10] = {13,13,10,10,10,13,13,13,13,13};
    const int oOf[10] = {0,80000,160000,220000,280000,340000,420000,500000,560000,620000};

    __shared__ __align__(16) unsigned char sAF[16384];  // 2 phases x (2 kc x 4 m-frags x 1 KB)
    __shared__ float lgt[8][64][2];

    int bid = blockIdx.x;
    int ty = 0;
    while (bid >= blkEnd[ty]) ty++;
    int lb = bid - (ty ? blkEnd[ty-1] : 0);
    int jT = jTl[ty];
    int it = lb / jT;
    int jt = lb - it*jT;
    int i0 = aB[ty] + it*4;
    int j0 = bB[ty] + jt*16;

    int tid  = threadIdx.x;
    int lane = tid & 63;
    int w    = tid >> 6;       // 0..7
    int w3_  = w & 3;          // m-frag it generates == n64-slice it owns
    int wh   = w >> 2;         // W2-half it owns == kc-slot it generates
    int l15  = lane & 15;
    int quad = lane >> 4;
    int kb   = (bid*7) & 31;   // per-block k-phase stagger

    // B frags: frag index = wh*512 + kc*16 + (w3_*4 + nf)
    const char* WB = (const char*)W2H + ((size_t)(wh*512 + w3_*4))*1024 + lane*16;
    const ushort_t* HBp = HB + (j0 + l15)*KDIM + quad*8;
    const ushort_t* HAp = HA + (i0 + w3_)*KDIM + quad*8;

    floatx4 acc[4][4];
#pragma unroll
    for (int mf = 0; mf < 4; ++mf)
#pragma unroll
        for (int nf = 0; nf < 4; ++nf) acc[mf][nf] = (floatx4){0.f,0.f,0.f,0.f};

    int k0 = kb, k1 = (kb + 1) & 31;
    bf16x8 Bc0 = *(const bf16x8*)(WB + (size_t)k0*16384);
    bf16x8 Bc1 = *(const bf16x8*)(WB + (size_t)k0*16384 + 1024);
    bf16x8 Bc2 = *(const bf16x8*)(WB + (size_t)k0*16384 + 2048);
    bf16x8 Bc3 = *(const bf16x8*)(WB + (size_t)k0*16384 + 3072);
    bf16x8 Bn0 = *(const bf16x8*)(WB + (size_t)k1*16384);
    bf16x8 Bn1 = *(const bf16x8*)(WB + (size_t)k1*16384 + 1024);
    bf16x8 Bn2 = *(const bf16x8*)(WB + (size_t)k1*16384 + 2048);
    bf16x8 Bn3 = *(const bf16x8*)(WB + (size_t)k1*16384 + 3072);

    int kg0 = (kb + wh) & 31;          // this wave's gen kc for phase 0
    bf16x8 ha = *(const bf16x8*)(HAp + kg0*32);
    bf16x8 hb = *(const bf16x8*)(HBp + kg0*32);

#pragma unroll 2
    for (int ph = 0; ph < 16; ++ph) {
        // A-gen: exactly one frag per wave -> LDS slot (kc-slot wh, m-frag w3_) = w*1024
        char* sW = (char*)sAF + (ph & 1)*8192 + w*1024 + lane*16;
        *(bf16x8*)sW = mk_af3(ha, hb);
        // next-phase ha/hb prefetch (full-phase distance; wraps harmlessly at ph=15)
        int kgn = (kb + 2*(ph + 1) + wh) & 31;
        ha = *(const bf16x8*)(HAp + kgn*32);
        hb = *(const bf16x8*)(HBp + kgn*32);
        LDS_BARRIER();

        const char* sR = (const char*)sAF + (ph & 1)*8192 + lane*16;
        int kn2 = (kb + 2*ph + 2) & 31;
        int kn3 = (kb + 2*ph + 3) & 31;
        // sub 0
        {
            bf16x8 a0 = *(const bf16x8*)(sR);
            bf16x8 a1 = *(const bf16x8*)(sR + 1024);
            bf16x8 a2 = *(const bf16x8*)(sR + 2048);
            bf16x8 a3 = *(const bf16x8*)(sR + 3072);
            acc[0][0] = MFMA(a0, Bc0, acc[0][0]); acc[1][0] = MFMA(a1, Bc0, acc[1][0]);
            acc[2][0] = MFMA(a2, Bc0, acc[2][0]); acc[3][0] = MFMA(a3, Bc0, acc[3][0]);
            acc[0][1] = MFMA(a0, Bc1, acc[0][1]); acc[1][1] = MFMA(a1, Bc1, acc[1][1]);
            acc[2][1] = MFMA(a2, Bc1, acc[2][1]); acc[3][1] = MFMA(a3, Bc1, acc[3][1]);
            acc[0][2] = MFMA(a0, Bc2, acc[0][2]); acc[1][2] = MFMA(a1, Bc2, acc[1][2]);
            acc[2][2] = MFMA(a2, Bc2, acc[2][2]); acc[3][2] = MFMA(a3, Bc2, acc[3][2]);
            acc[0][3] = MFMA(a0, Bc3, acc[0][3]); acc[1][3] = MFMA(a1, Bc3, acc[1][3]);
            acc[2][3] = MFMA(a2, Bc3, acc[2][3]); acc[3][3] = MFMA(a3, Bc3, acc[3][3]);
        }
        Bc0 = *(const bf16x8*)(WB + (size_t)kn2*16384);
        Bc1 = *(const bf16x8*)(WB + (size_t)kn2*16384 + 1024);
        Bc2 = *(const bf16x8*)(WB + (size_t)kn2*16384 + 2048);
        Bc3 = *(const bf16x8*)(WB + (size_t)kn2*16384 + 3072);
        // sub 1
        {
            bf16x8 a0 = *(const bf16x8*)(sR + 4096);
            bf16x8 a1 = *(const bf16x8*)(sR + 4096 + 1024);
            bf16x8 a2 = *(const bf16x8*)(sR + 4096 + 2048);
            bf16x8 a3 = *(const bf16x8*)(sR + 4096 + 3072);
            acc[0][0] = MFMA(a0, Bn0, acc[0][0]); acc[1][0] = MFMA(a1, Bn0, acc[1][0]);
            acc[2][0] = MFMA(a2, Bn0, acc[2][0]); acc[3][0] = MFMA(a3, Bn0, acc[3][0]);
            acc[0][1] = MFMA(a0, Bn1, acc[0][1]); acc[1][1] = MFMA(a1, Bn1, acc[1][1]);
            acc[2][1] = MFMA(a2, Bn1, acc[2][1]); acc[3][1] = MFMA(a3, Bn1, acc[3][1]);
            acc[0][2] = MFMA(a0, Bn2, acc[0][2]); acc[1][2] = MFMA(a1, Bn2, acc[1][2]);
            acc[2][2] = MFMA(a2, Bn2, acc[2][2]); acc[3][2] = MFMA(a3, Bn2, acc[3][2]);
            acc[0][3] = MFMA(a0, Bn3, acc[0][3]); acc[1][3] = MFMA(a1, Bn3, acc[1][3]);
            acc[2][3] = MFMA(a2, Bn3, acc[2][3]); acc[3][3] = MFMA(a3, Bn3, acc[3][3]);
        }
        Bn0 = *(const bf16x8*)(WB + (size_t)kn3*16384);
        Bn1 = *(const bf16x8*)(WB + (size_t)kn3*16384 + 1024);
        Bn2 = *(const bf16x8*)(WB + (size_t)kn3*16384 + 2048);
        Bn3 = *(const bf16x8*)(WB + (size_t)kn3*16384 + 3072);
    }

    // epilogue: h2 = relu(acc + b2); partial logits over this wave's n64; LDS reduce across 8 waves
    int isbf = detect_bf16((const ushort_t*)E);
    int nb = wh*256 + w3_*64;
    float b2v[4], wa[4], wb[4];
#pragma unroll
    for (int nf = 0; nf < 4; ++nf) {
        int n = nb + nf*16 + l15;
        b2v[nf] = ldin(b2, n, isbf);
        wa[nf]  = ldin(W3, 2*n, isbf);
        wb[nf]  = ldin(W3, 2*n+1, isbf);
    }
#pragma unroll
    for (int mf = 0; mf < 4; ++mf) {
        float s0[4] = {0.f,0.f,0.f,0.f};
        float s1[4] = {0.f,0.f,0.f,0.f};
#pragma unroll
        for (int nf = 0; nf < 4; ++nf) {
            floatx4 c = acc[mf][nf];
#pragma unroll
            for (int r = 0; r < 4; ++r) {
                float v = fmaxf(c[r] + b2v[nf], 0.f);
                s0[r] += v * wa[nf];
                s1[r] += v * wb[nf];
            }
        }
#pragma unroll
        for (int off = 1; off < 16; off <<= 1) {
#pragma unroll
            for (int r = 0; r < 4; ++r) {
                s0[r] += __shfl_xor(s0[r], off, 64);
                s1[r] += __shfl_xor(s1[r], off, 64);
            }
        }
        if (l15 == 0) {
#pragma unroll
            for (int r = 0; r < 4; ++r) {
                int p = mf*16 + quad*4 + r;
                lgt[w][p][0] = s0[r];
                lgt[w][p][1] = s1[r];
            }
        }
    }
    __syncthreads();

    if (tid < 64) {
        int p = tid;
        float l0 = 0.f, l1 = 0.f;
#pragma unroll
        for (int ww = 0; ww < 8; ++ww) { l0 += lgt[ww][p][0]; l1 += lgt[ww][p][1]; }
        l0 += ldin(b3, 0, isbf);
        l1 += ldin(b3, 1, isbf);
        int pi = it*4 + (p >> 4), pj = jt*16 + (p & 15);
        if (pi < NaT[ty] && pj < NbT[ty]) {
            float mx = fmaxf(l0, l1);
            float e0 = __expf(l0 - mx), e1 = __expf(l1 - mx);
            float inv = 1.f / (e0 + e1);
            int o = oOf[ty] + (pi*NbT[ty] + pj)*2;
            if (isbf) {
                __hip_bfloat16* ob = (__hip_bfloat16*)out;
                ob[o]   = __float2bfloat16(e0 * inv);
                ob[o+1] = __float2bfloat16(e1 * inv);
            } else {
                float* of = (float*)out;
                of[o]   = e0 * inv;
                of[o+1] = e1 * inv;
            }
        }
    }
}

extern "C" void kernel_launch(void* const* d_in, const int* in_sizes, int n_in,
                              void* d_out, int out_size, void* d_ws, size_t ws_size,
                              hipStream_t stream) {
    const void* E    = d_in[1];
    const void* Went = d_in[3];
    const void* W1   = d_in[5];
    const void* b1   = d_in[6];
    const void* W2   = d_in[7];
    const void* b2   = d_in[8];
    const void* W3   = d_in[9];
    const void* b3   = d_in[10];

    char* ws = (char*)d_ws;
    __hip_bfloat16* HA   = (__hip_bfloat16*)(ws + WS_HA);
    __hip_bfloat16* HB   = (__hip_bfloat16*)(ws + WS_HB);
    __hip_bfloat16* W2H  = (__hip_bfloat16*)(ws + WS_W2H);
    float*          entf = (float*)(ws + WS_ENT);

    entprep_kernel<<<dim3(344), dim3(256), 0, stream>>>(E, Went, W2, entf, W2H, d_out);
    hab_kernel<<<dim3(45, 2), dim3(256), 0, stream>>>(entf, E, W1, b1, HA, HB);
    pair_kernel<<<dim3(5582), dim3(512), 0, stream>>>((const ushort_t*)HA, (const ushort_t*)HB,
                                                      (const ushort_t*)W2H, E, b2, W3, b3, d_out);
}

// Round 4
// 507.052 us; speedup vs baseline: 1.1107x; 1.1100x over previous
//
#include <hip/hip_runtime.h>
#include <hip/hip_bf16.h>

typedef __attribute__((ext_vector_type(4))) float floatx4;
typedef __attribute__((ext_vector_type(8))) __bf16 bf16x8;
typedef unsigned short ushort_t;

#define NENT  700
#define EMB   256
#define KDIM  1024
#define NDIM  512
#define HROWS 720   // 45*16: every row written by hab_kernel; reads stay <= 709
#define NPAIR 340000

// ws byte offsets — total ~7.4 MB
#define WS_HA   0
#define WS_HB   (WS_HA + HROWS*KDIM*2)
#define WS_W2H  (WS_HB + HROWS*KDIM*2)
#define WS_ENT  (WS_W2H + NDIM*KDIM*2)
#define WS_LG   (WS_ENT + NENT*EMB*4)

__device__ __forceinline__ float ldin(const void* p, int i, int isbf) {
    return isbf ? __bfloat162float(((const __hip_bfloat16*)p)[i])
                : ((const float*)p)[i];
}

// per-wave dtype sniff of entity_embedding; deterministic, no cross-kernel dep
__device__ __forceinline__ int detect_bf16(const ushort_t* __restrict__ w) {
    int t = threadIdx.x & 63;
    int e = (w[2*t] >> 7) & 0xFF;
    unsigned long long m = __ballot(e >= 100 && e <= 126);
    return (__popcll(m) >= 48) ? 1 : 0;   // bf16 ~64 hits, f32 ~7
}

// lgkmcnt(0) only; vmcnt untouched -> global prefetches survive the barrier
#define LDS_BARRIER() do { __builtin_amdgcn_s_waitcnt(0xC07F); __builtin_amdgcn_s_barrier(); } while (0)

// ---------------- stage 1: ent (88 blocks) + W2 repack (256 blocks), one launch ----------------
__global__ void entprep_kernel(const void* __restrict__ E, const void* __restrict__ Went,
                               const void* __restrict__ W2,
                               float* __restrict__ ent, __hip_bfloat16* __restrict__ W2H,
                               void* __restrict__ out) {
    int isbf = detect_bf16((const ushort_t*)E);
    if (blockIdx.x < 88) {
        int ib = blockIdx.x * 8, t = threadIdx.x;
        __shared__ float rows[8][EMB];
#pragma unroll
        for (int r = 0; r < 8; ++r) {
            int i = ib + r;
            rows[r][t] = (i < NENT) ? ldin(E, i*EMB + t, isbf) : 0.f;
        }
        __syncthreads();
        float acc[8] = {0.f,0.f,0.f,0.f,0.f,0.f,0.f,0.f};
        if (isbf) {
            const __hip_bfloat16* W = (const __hip_bfloat16*)Went;
            for (int k = 0; k < EMB; ++k) {
                float w = __bfloat162float(W[k*EMB + t]);
#pragma unroll
                for (int r = 0; r < 8; ++r) acc[r] += rows[r][k] * w;
            }
        } else {
            const float* W = (const float*)Went;
            for (int k = 0; k < EMB; ++k) {
                float w = W[k*EMB + t];
#pragma unroll
                for (int r = 0; r < 8; ++r) acc[r] += rows[r][k] * w;
            }
        }
#pragma unroll
        for (int r = 0; r < 8; ++r) {
            int i = ib + r;
            if (i < NENT) {
                ent[i*EMB + t] = acc[r];
                if (i < 200) {
                    if (isbf) ((__hip_bfloat16*)out)[680000 + i*EMB + t] = __float2bfloat16(acc[r]);
                    else      ((float*)out)[680000 + i*EMB + t] = acc[r];
                }
            }
        }
    } else {
        // W2H: elem ((half*32+kc)*16 + f)*512 + lane*8 + j
        //   = bf16(W2[(kc*32 + (lane>>4)*8 + j)*512 + half*256 + f*16 + (lane&15)])
        int g = (blockIdx.x - 88)*256 + threadIdx.x;     // 65536
        int lane = g & 63, f = (g >> 6) & 15, kc = (g >> 10) & 31, half = g >> 15;
        int l15 = lane & 15, quad = lane >> 4;
        int n = half*256 + f*16 + l15;
        bf16x8 v;
#pragma unroll
        for (int j = 0; j < 8; ++j) {
            int k = kc*32 + quad*8 + j;
            v[j] = (__bf16)ldin(W2, k*NDIM + n, isbf);
        }
        *(bf16x8*)(W2H + (size_t)g*8) = v;
    }
}

// ---------------- stage 2: HA/HB, 16 rows/block ----------------
__global__ void hab_kernel(const float* __restrict__ ent, const void* __restrict__ E,
                           const void* __restrict__ W1, const void* __restrict__ b1,
                           __hip_bfloat16* __restrict__ HA, __hip_bfloat16* __restrict__ HB) {
    int isbf = detect_bf16((const ushort_t*)E);
    int part = blockIdx.y;
    int ib = blockIdx.x * 16;
    int t = threadIdx.x;
    __shared__ float rows[16][EMB];
#pragma unroll
    for (int r = 0; r < 16; ++r) {
        int i = ib + r;
        rows[r][t] = (i < NENT) ? ent[i*EMB + t] : 0.f;
    }
    __syncthreads();
    float acc[16][4];
#pragma unroll
    for (int r = 0; r < 16; ++r)
#pragma unroll
        for (int p = 0; p < 4; ++p) acc[r][p] = 0.f;

    int wbase = part*EMB*KDIM;
    if (isbf) {
        const __hip_bfloat16* W = (const __hip_bfloat16*)W1;
        for (int k = 0; k < EMB; ++k) {
            float w[4];
#pragma unroll
            for (int p = 0; p < 4; ++p) w[p] = __bfloat162float(W[wbase + k*KDIM + t + p*256]);
#pragma unroll
            for (int r = 0; r < 16; ++r) {
                float e = rows[r][k];
#pragma unroll
                for (int p = 0; p < 4; ++p) acc[r][p] += e * w[p];
            }
        }
    } else {
        const float* W = (const float*)W1;
        for (int k = 0; k < EMB; ++k) {
            float w[4];
#pragma unroll
            for (int p = 0; p < 4; ++p) w[p] = W[wbase + k*KDIM + t + p*256];
#pragma unroll
            for (int r = 0; r < 16; ++r) {
                float e = rows[r][k];
#pragma unroll
                for (int p = 0; p < 4; ++p) acc[r][p] += e * w[p];
            }
        }
    }
    __hip_bfloat16* HX = part ? HB : HA;
#pragma unroll
    for (int r = 0; r < 16; ++r) {
#pragma unroll
        for (int p = 0; p < 4; ++p) {
            int n = t + p*256;
            float v = acc[r][p];
            if (!part) v += ldin(b1, n, isbf);
            HX[(ib + r)*KDIM + n] = __float2bfloat16(v);
        }
    }
}

union U8 { bf16x8 v; unsigned u[4]; };

// relu(ha + hb) -> bf16 round-half-up, pair-packed via v_perm
__device__ __forceinline__ bf16x8 mk_af3(bf16x8 ha, bf16x8 hb) {
    U8 r;
#pragma unroll
    for (int j = 0; j < 4; ++j) {
        float x0 = fmaxf((float)ha[2*j]   + (float)hb[2*j],   0.f);
        float x1 = fmaxf((float)ha[2*j+1] + (float)hb[2*j+1], 0.f);
        unsigned u0 = __float_as_uint(x0) + 0x8000u;
        unsigned u1 = __float_as_uint(x1) + 0x8000u;
#if defined(__has_builtin) && __has_builtin(__builtin_amdgcn_perm)
        r.u[j] = __builtin_amdgcn_perm(u1, u0, 0x07060302u);  // {u1.hi16, u0.hi16}
#else
        r.u[j] = (u0 >> 16) | (u1 & 0xFFFF0000u);
#endif
    }
    return r.v;
}

#define MFMA(a, b, c) __builtin_amdgcn_mfma_f32_16x16x32_bf16((a), (b), (c), 0, 0, 0)

// ---------------- main: fused pair MLP ----------------
// R16: M=128 tile (8 i-rows x 16 j-rows = 128 pairs/block). R15 post-mortem
// showed the 35% MfmaUtil plateau is the 2-barrier-per-K-step structural
// ceiling (same 35% at 1 and 3 blocks/CU; memory far from any wall). Doubling
// the MFMA batch per barrier amortizes the fixed per-phase stall, and each
// 1MB W2H sweep now covers 2x pairs (B-loads per FLOP halved). Wave w
// generates A-frags (m=w, kc=0/1); owns n64-slice w. acc[8][4] = 128 AGPR,
// ~220 regs total -> still 2 waves/SIMD. B-side addressing unchanged.
__global__ __launch_bounds__(512, 2) void pair_kernel(
        const ushort_t* __restrict__ HA, const ushort_t* __restrict__ HB,
        const ushort_t* __restrict__ W2H, const void* __restrict__ E,
        const void* __restrict__ b2, const void* __restrict__ W3,
        const void* __restrict__ b3, void* __restrict__ out) {

    // per-type i-tiles = ceil(Na/8), j-tiles = ceil(Nb/16)
    const int blkEnd[10] = {325,650,900,1150,1400,1725,2050,2297,2544,2791};
    const int aB[10]  = {0,0,0,0,200,200,200,550,400,400};
    const int bB[10]  = {200,0,400,550,400,200,0,0,200,0};
    const int NaT[10] = {200,200,200,200,200,200,200,150,150,150};
    const int NbT[10] = {200,200,150,150,150,200,200,200,200,200};
    const int jTl[10] = {13,13,10,10,10,13,13,13,13,13};
    const int oOf[10] = {0,80000,160000,220000,280000,340000,420000,500000,560000,620000};

    __shared__ __align__(16) unsigned char sAF[32768];  // 2 phases x (2 kc x 8 m-frags x 1 KB)
    __shared__ float lgt[8][128][2];

    int bid = blockIdx.x;
    int ty = 0;
    while (bid >= blkEnd[ty]) ty++;
    int lb = bid - (ty ? blkEnd[ty-1] : 0);
    int jT = jTl[ty];
    int it = lb / jT;
    int jt = lb - it*jT;
    int i0 = aB[ty] + it*8;
    int j0 = bB[ty] + jt*16;

    int tid  = threadIdx.x;
    int lane = tid & 63;
    int w    = tid >> 6;       // 0..7: A m-frag it generates AND n64-slice it owns
    int l15  = lane & 15;
    int quad = lane >> 4;
    int kb   = (bid*7) & 31;   // per-block k-phase stagger

    // B frags: frag index = (w>>2)*512 + kc*16 + ((w&3)*4 + nf)  [unchanged layout]
    const char* WB = (const char*)W2H + ((size_t)((w>>2)*512 + (w&3)*4))*1024 + lane*16;
    const ushort_t* HBp = HB + (j0 + l15)*KDIM + quad*8;
    const ushort_t* HAp = HA + (i0 + w)*KDIM + quad*8;

    floatx4 acc[8][4];
#pragma unroll
    for (int mf = 0; mf < 8; ++mf)
#pragma unroll
        for (int nf = 0; nf < 4; ++nf) acc[mf][nf] = (floatx4){0.f,0.f,0.f,0.f};

    int k0 = kb, k1 = (kb + 1) & 31;
    bf16x8 Bc0 = *(const bf16x8*)(WB + (size_t)k0*16384);
    bf16x8 Bc1 = *(const bf16x8*)(WB + (size_t)k0*16384 + 1024);
    bf16x8 Bc2 = *(const bf16x8*)(WB + (size_t)k0*16384 + 2048);
    bf16x8 Bc3 = *(const bf16x8*)(WB + (size_t)k0*16384 + 3072);
    bf16x8 Bn0 = *(const bf16x8*)(WB + (size_t)k1*16384);
    bf16x8 Bn1 = *(const bf16x8*)(WB + (size_t)k1*16384 + 1024);
    bf16x8 Bn2 = *(const bf16x8*)(WB + (size_t)k1*16384 + 2048);
    bf16x8 Bn3 = *(const bf16x8*)(WB + (size_t)k1*16384 + 3072);

    // each wave generates its m-frag for BOTH kc slots -> needs both k chunks
    bf16x8 haA = *(const bf16x8*)(HAp + k0*32);
    bf16x8 haB = *(const bf16x8*)(HAp + k1*32);
    bf16x8 hbA = *(const bf16x8*)(HBp + k0*32);
    bf16x8 hbB = *(const bf16x8*)(HBp + k1*32);

#pragma unroll 2
    for (int ph = 0; ph < 16; ++ph) {
        // A-gen: 2 frags per wave -> LDS slots (kc0: w*1KB), (kc1: 8KB + w*1KB)
        char* sW = (char*)sAF + (ph & 1)*16384 + w*1024 + lane*16;
        *(bf16x8*)(sW)        = mk_af3(haA, hbA);
        *(bf16x8*)(sW + 8192) = mk_af3(haB, hbB);
        // next-phase ha/hb prefetch (full-phase distance; wraps harmlessly at ph=15)
        int kn2 = (kb + 2*ph + 2) & 31;
        int kn3 = (kb + 2*ph + 3) & 31;
        haA = *(const bf16x8*)(HAp + kn2*32);
        haB = *(const bf16x8*)(HAp + kn3*32);
        hbA = *(const bf16x8*)(HBp + kn2*32);
        hbB = *(const bf16x8*)(HBp + kn3*32);
        LDS_BARRIER();

        const char* sR = (const char*)sAF + (ph & 1)*16384 + lane*16;
        // sub 0 (kc0): 8 m-frags x 4 n-frags
        {
#pragma unroll
            for (int mf = 0; mf < 8; ++mf) {
                bf16x8 a = *(const bf16x8*)(sR + mf*1024);
                acc[mf][0] = MFMA(a, Bc0, acc[mf][0]);
                acc[mf][1] = MFMA(a, Bc1, acc[mf][1]);
                acc[mf][2] = MFMA(a, Bc2, acc[mf][2]);
                acc[mf][3] = MFMA(a, Bc3, acc[mf][3]);
            }
        }
        Bc0 = *(const bf16x8*)(WB + (size_t)kn2*16384);
        Bc1 = *(const bf16x8*)(WB + (size_t)kn2*16384 + 1024);
        Bc2 = *(const bf16x8*)(WB + (size_t)kn2*16384 + 2048);
        Bc3 = *(const bf16x8*)(WB + (size_t)kn2*16384 + 3072);
        // sub 1 (kc1)
        {
#pragma unroll
            for (int mf = 0; mf < 8; ++mf) {
                bf16x8 a = *(const bf16x8*)(sR + 8192 + mf*1024);
                acc[mf][0] = MFMA(a, Bn0, acc[mf][0]);
                acc[mf][1] = MFMA(a, Bn1, acc[mf][1]);
                acc[mf][2] = MFMA(a, Bn2, acc[mf][2]);
                acc[mf][3] = MFMA(a, Bn3, acc[mf][3]);
            }
        }
        Bn0 = *(const bf16x8*)(WB + (size_t)kn3*16384);
        Bn1 = *(const bf16x8*)(WB + (size_t)kn3*16384 + 1024);
        Bn2 = *(const bf16x8*)(WB + (size_t)kn3*16384 + 2048);
        Bn3 = *(const bf16x8*)(WB + (size_t)kn3*16384 + 3072);
    }

    // epilogue: h2 = relu(acc + b2); partial logits over this wave's n64; LDS reduce across 8 waves
    int isbf = detect_bf16((const ushort_t*)E);
    int nb = w*64;
    float b2v[4], wa[4], wb[4];
#pragma unroll
    for (int nf = 0; nf < 4; ++nf) {
        int n = nb + nf*16 + l15;
        b2v[nf] = ldin(b2, n, isbf);
        wa[nf]  = ldin(W3, 2*n, isbf);
        wb[nf]  = ldin(W3, 2*n+1, isbf);
    }
#pragma unroll
    for (int mf = 0; mf < 8; ++mf) {
        float s0[4] = {0.f,0.f,0.f,0.f};
        float s1[4] = {0.f,0.f,0.f,0.f};
#pragma unroll
        for (int nf = 0; nf < 4; ++nf) {
            floatx4 c = acc[mf][nf];
#pragma unroll
            for (int r = 0; r < 4; ++r) {
                float v = fmaxf(c[r] + b2v[nf], 0.f);
                s0[r] += v * wa[nf];
                s1[r] += v * wb[nf];
            }
        }
#pragma unroll
        for (int off = 1; off < 16; off <<= 1) {
#pragma unroll
            for (int r = 0; r < 4; ++r) {
                s0[r] += __shfl_xor(s0[r], off, 64);
                s1[r] += __shfl_xor(s1[r], off, 64);
            }
        }
        if (l15 == 0) {
#pragma unroll
            for (int r = 0; r < 4; ++r) {
                int p = mf*16 + quad*4 + r;
                lgt[w][p][0] = s0[r];
                lgt[w][p][1] = s1[r];
            }
        }
    }
    __syncthreads();

    if (tid < 128) {
        int p = tid;
        float l0 = 0.f, l1 = 0.f;
#pragma unroll
        for (int ww = 0; ww < 8; ++ww) { l0 += lgt[ww][p][0]; l1 += lgt[ww][p][1]; }
        l0 += ldin(b3, 0, isbf);
        l1 += ldin(b3, 1, isbf);
        int pi = it*8 + (p >> 4), pj = jt*16 + (p & 15);
        if (pi < NaT[ty] && pj < NbT[ty]) {
            float mx = fmaxf(l0, l1);
            float e0 = __expf(l0 - mx), e1 = __expf(l1 - mx);
            float inv = 1.f / (e0 + e1);
            int o = oOf[ty] + (pi*NbT[ty] + pj)*2;
            if (isbf) {
                __hip_bfloat16* ob = (__hip_bfloat16*)out;
                ob[o]   = __float2bfloat16(e0 * inv);
                ob[o+1] = __float2bfloat16(e1 * inv);
            } else {
                float* of = (float*)out;
                of[o]   = e0 * inv;
                of[o+1] = e1 * inv;
            }
        }
    }
}

extern "C" void kernel_launch(void* const* d_in, const int* in_sizes, int n_in,
                              void* d_out, int out_size, void* d_ws, size_t ws_size,
                              hipStream_t stream) {
    const void* E    = d_in[1];
    const void* Went = d_in[3];
    const void* W1   = d_in[5];
    const void* b1   = d_in[6];
    const void* W2   = d_in[7];
    const void* b2   = d_in[8];
    const void* W3   = d_in[9];
    const void* b3   = d_in[10];

    char* ws = (char*)d_ws;
    __hip_bfloat16* HA   = (__hip_bfloat16*)(ws + WS_HA);
    __hip_bfloat16* HB   = (__hip_bfloat16*)(ws + WS_HB);
    __hip_bfloat16* W2H  = (__hip_bfloat16*)(ws + WS_W2H);
    float*          entf = (float*)(ws + WS_ENT);

    entprep_kernel<<<dim3(344), dim3(256), 0, stream>>>(E, Went, W2, entf, W2H, d_out);
    hab_kernel<<<dim3(45, 2), dim3(256), 0, stream>>>(entf, E, W1, b1, HA, HB);
    pair_kernel<<<dim3(2791), dim3(512), 0, stream>>>((const ushort_t*)HA, (const ushort_t*)HB,
                                                      (const ushort_t*)W2H, E, b2, W3, b3, d_out);
}